// Round 1
// baseline (300.768 us; speedup 1.0000x reference)
//
#include <hip/hip_runtime.h>
#include <hip/hip_bf16.h>
#include <stdint.h>

#define B_ 32
#define S_ 512
#define D_ 768
#define O_ 768
#define E_ 8
#define YSIZE (B_ * S_ * O_)   // 12582912
#define BK 32

typedef __attribute__((ext_vector_type(8))) short bf16x8;
typedef __attribute__((ext_vector_type(4))) float f32x4;

static __device__ __forceinline__ unsigned short f2bf(float f) {
  union { float f; uint32_t u; } v; v.f = f;
  uint32_t u = v.u;
  uint32_t r = u + 0x7fff + ((u >> 16) & 1);   // RNE
  return (unsigned short)(r >> 16);
}

static __device__ __forceinline__ void async_load16(const void* g, void* l) {
  __builtin_amdgcn_global_load_lds(
      (const __attribute__((address_space(1))) void*)g,
      (__attribute__((address_space(3))) void*)l, 16, 0, 0);
}

// ---------------- Kernel 1: pool partial sums + x -> bf16 ----------------
// grid (3, 32, 4), block 256. Reads all of x once (coalesced), writes bf16 x
// and per-(chunk,b,d) partial sums.
__global__ void k_pool_convert(const float* __restrict__ x,
                               unsigned short* __restrict__ xb,
                               float* __restrict__ psum) {
  int d  = blockIdx.x * 256 + threadIdx.x;   // 0..767
  int b  = blockIdx.y;
  int sc = blockIdx.z;                        // 0..3, 128 s each
  const float* xp = x + ((size_t)(b * S_ + sc * 128)) * D_ + d;
  unsigned short* op = xb + ((size_t)(b * S_ + sc * 128)) * D_ + d;
  float sum = 0.f;
  #pragma unroll 8
  for (int s = 0; s < 128; ++s) {
    float v = xp[(size_t)s * D_];
    sum += v;
    op[(size_t)s * D_] = f2bf(v);
  }
  psum[(sc * B_ + b) * D_ + d] = sum;
}

// ---------------- Kernel 2: gating + loss + combined bias ----------------
// single block, 256 threads
__global__ void k_gate(const float* __restrict__ psum,
                       const float* __restrict__ w_gate,
                       const float* __restrict__ bias,
                       float* __restrict__ cb,
                       int* __restrict__ eidx, float* __restrict__ gval,
                       float* __restrict__ loss_out) {
  __shared__ float logits[B_][E_];
  __shared__ float gates[B_][E_];
  __shared__ int   sh_e[2][B_];
  __shared__ float sh_g[2][B_];
  __shared__ float imp[E_], loadv[E_];
  int tid = threadIdx.x;

  // logits: thread (b,e) does a 768-dot
  {
    int b = tid >> 3, e = tid & 7;
    float acc = 0.f;
    #pragma unroll 4
    for (int d = 0; d < D_; ++d) {
      float pooled = (psum[b * D_ + d] + psum[(B_ + b) * D_ + d] +
                      psum[(2 * B_ + b) * D_ + d] + psum[(3 * B_ + b) * D_ + d]) *
                     (1.0f / (float)S_);
      acc += pooled * w_gate[d * E_ + e];
    }
    logits[b][e] = acc;
    gates[b][e] = 0.f;
  }
  __syncthreads();

  if (tid < B_) {
    int b = tid;
    int i0 = 0; float v0 = logits[b][0];
    #pragma unroll
    for (int e = 1; e < E_; ++e) { float v = logits[b][e]; if (v > v0) { v0 = v; i0 = e; } }
    int i1 = -1; float v1 = -1e30f;
    #pragma unroll
    for (int e = 0; e < E_; ++e) {
      if (e == i0) continue;
      float v = logits[b][e]; if (v > v1) { v1 = v; i1 = e; }
    }
    float m  = fmaxf(v0, v1);
    float e0 = expf(v0 - m), e1 = expf(v1 - m);
    float s  = e0 + e1;
    float g0 = e0 / s, g1 = e1 / s;
    gates[b][i0] = g0; gates[b][i1] = g1;
    sh_e[0][b] = i0; sh_e[1][b] = i1;
    sh_g[0][b] = g0; sh_g[1][b] = g1;
    eidx[b] = i0; eidx[B_ + b] = i1;
    gval[b] = g0; gval[B_ + b] = g1;
  }
  __syncthreads();

  if (tid < E_) {
    float s = 0.f, c = 0.f;
    for (int b = 0; b < B_; ++b) {
      float g = gates[b][tid];
      s += g;
      c += (g > 0.f) ? 1.f : 0.f;
    }
    imp[tid] = s; loadv[tid] = c;
  }
  __syncthreads();

  if (tid == 0) {
    double mi = 0, ml = 0;
    for (int e = 0; e < E_; ++e) { mi += imp[e]; ml += loadv[e]; }
    mi /= E_; ml /= E_;
    double vi = 0, vl = 0;
    for (int e = 0; e < E_; ++e) {
      double di = imp[e] - mi, dl = loadv[e] - ml;
      vi += di * di; vl += dl * dl;
    }
    vi /= (E_ - 1); vl /= (E_ - 1);
    double cvi = vi / (mi * mi + 1e-10);
    double cvl = vl / (ml * ml + 1e-10);
    loss_out[0] = (float)((cvi + cvl) * 0.01);
  }
  __syncthreads();

  // combined bias: cb[b][o] = g0*bias[e0][o] + g1*bias[e1][o]
  for (int o = tid; o < O_; o += 256) {
    for (int b = 0; b < B_; ++b) {
      cb[b * O_ + o] = sh_g[0][b] * bias[sh_e[0][b] * O_ + o] +
                       sh_g[1][b] * bias[sh_e[1][b] * O_ + o];
    }
  }
}

// ---------------- Kernel 3: batched GEMM y[b] = x[b] @ Wc[b]^T + cb[b] ----
// 128x128 tile, BK=32, 4 waves (2x2), each wave 64x64 (4x4 of 16x16x32 MFMA).
// A (bf16 x) staged via global_load_lds width=16; B combined on the fly from
// two fp32 expert weights (L2/L3-resident), packed to bf16 in LDS.
__global__ __launch_bounds__(256) void k_moe_gemm(
    const unsigned short* __restrict__ xb, const float* __restrict__ weight,
    const int* __restrict__ eidx, const float* __restrict__ gval,
    const float* __restrict__ cb, float* __restrict__ y) {
  __shared__ unsigned short Alds[128 * BK];  // 8 KB
  __shared__ unsigned short Blds[128 * BK];  // 8 KB

  int b    = blockIdx.y;
  int tile = blockIdx.x;
  int st = tile & 3;          // S tile 0..3
  int ot = tile >> 2;         // O tile 0..5
  int s0 = st * 128, o0 = ot * 128;

  int tid  = threadIdx.x;
  int wave = tid >> 6, lane = tid & 63;
  int wm = wave & 1, wn = wave >> 1;

  int   e0 = eidx[b], e1 = eidx[B_ + b];
  float g0 = gval[b], g1 = gval[B_ + b];

  const unsigned short* Abase = xb + ((size_t)(b * S_ + s0)) * D_;
  const float* W0 = weight + (size_t)e0 * O_ * D_ + (size_t)o0 * D_;
  const float* W1 = weight + (size_t)e1 * O_ * D_ + (size_t)o0 * D_;

  int brow  = tid >> 1;   // 0..127
  int bhalf = tid & 1;    // k sub-offset 0/16

  f32x4 acc[4][4];
  #pragma unroll
  for (int i = 0; i < 4; ++i)
    #pragma unroll
    for (int j = 0; j < 4; ++j) acc[i][j] = (f32x4){0.f, 0.f, 0.f, 0.f};

  int a_chunk0 = wave * 2;
  int a_r = lane >> 2;        // row within 16-row chunk
  int a_c = (lane & 3) * 8;   // col element (8 bf16 = 16B)

  for (int kk = 0; kk < D_; kk += BK) {
    __syncthreads();
    // --- A: async global->LDS, 2x 1KB chunks per wave (row-major 128x32) ---
    #pragma unroll
    for (int j = 0; j < 2; ++j) {
      int chunk = a_chunk0 + j;
      const unsigned short* src =
          Abase + (size_t)(chunk * 16 + a_r) * D_ + kk + a_c;
      async_load16(src, Alds + chunk * 512);
    }
    // --- B: load fp32 from both experts, combine, pack bf16, ds_write ---
    {
      const float* p0 = W0 + (size_t)brow * D_ + kk + bhalf * 16;
      const float* p1 = W1 + (size_t)brow * D_ + kk + bhalf * 16;
      uint32_t pk[8];
      #pragma unroll
      for (int i = 0; i < 4; ++i) {
        float4 u0 = ((const float4*)p0)[i];
        float4 u1 = ((const float4*)p1)[i];
        float c0 = g0 * u0.x + g1 * u1.x;
        float c1 = g0 * u0.y + g1 * u1.y;
        float c2 = g0 * u0.z + g1 * u1.z;
        float c3 = g0 * u0.w + g1 * u1.w;
        pk[i * 2 + 0] = (uint32_t)f2bf(c0) | ((uint32_t)f2bf(c1) << 16);
        pk[i * 2 + 1] = (uint32_t)f2bf(c2) | ((uint32_t)f2bf(c3) << 16);
      }
      uint32_t* dst = (uint32_t*)(Blds + brow * 32 + bhalf * 16);
      ((uint4*)dst)[0] = make_uint4(pk[0], pk[1], pk[2], pk[3]);
      ((uint4*)dst)[1] = make_uint4(pk[4], pk[5], pk[6], pk[7]);
    }
    __syncthreads();   // compiler drains vmcnt(0) here -> A chunks landed

    // --- fragments + MFMA ---
    bf16x8 af[4], bfr[4];
    int koff = (lane >> 4) * 8;
    int r16  = lane & 15;
    #pragma unroll
    for (int mi = 0; mi < 4; ++mi)
      af[mi] = *(const bf16x8*)(Alds + (wm * 64 + mi * 16 + r16) * BK + koff);
    #pragma unroll
    for (int ni = 0; ni < 4; ++ni)
      bfr[ni] = *(const bf16x8*)(Blds + (wn * 64 + ni * 16 + r16) * BK + koff);
    #pragma unroll
    for (int mi = 0; mi < 4; ++mi)
      #pragma unroll
      for (int ni = 0; ni < 4; ++ni)
        acc[mi][ni] = __builtin_amdgcn_mfma_f32_16x16x32_bf16(
            af[mi], bfr[ni], acc[mi][ni], 0, 0, 0);
  }

  // --- epilogue: y = acc + cb ---
  float* Y = y + ((size_t)(b * S_ + s0)) * O_ + o0;
  int col   = lane & 15;
  int rquad = (lane >> 4) * 4;
  #pragma unroll
  for (int ni = 0; ni < 4; ++ni) {
    int n = wn * 64 + ni * 16 + col;
    float cbv = cb[b * O_ + o0 + n];
    #pragma unroll
    for (int mi = 0; mi < 4; ++mi) {
      #pragma unroll
      for (int r = 0; r < 4; ++r) {
        int m = wm * 64 + mi * 16 + rquad + r;
        Y[(size_t)m * O_ + n] = acc[mi][ni][r] + cbv;
      }
    }
  }
}

// ---------------- launcher ----------------
// ws layout (bytes):
//   [0,           393216)  psum   float[4*32*768]
//   [393216,      491520)  cb     float[32*768]
//   [491520,      491776)  eidx   int[64]   (e0[32], e1[32])
//   [491776,      492032)  gval   float[64] (g0[32], g1[32])
//   [524288,    25690112)  x_bf16 ushort[32*512*768]
// total ws needed: ~25.7 MB
extern "C" void kernel_launch(void* const* d_in, const int* in_sizes, int n_in,
                              void* d_out, int out_size, void* d_ws, size_t ws_size,
                              hipStream_t stream) {
  const float* x      = (const float*)d_in[0];
  const float* w_gate = (const float*)d_in[1];
  const float* weight = (const float*)d_in[2];
  const float* bias   = (const float*)d_in[3];
  float* y = (float*)d_out;

  float* psum = (float*)d_ws;
  float* cbuf = psum + 4 * B_ * D_;
  int*   eidx = (int*)(cbuf + B_ * O_);
  float* gval = (float*)(eidx + 64);
  unsigned short* xb = (unsigned short*)((char*)d_ws + 524288);

  k_pool_convert<<<dim3(3, 32, 4), 256, 0, stream>>>(x, xb, psum);
  k_gate<<<1, 256, 0, stream>>>(psum, w_gate, bias, cbuf, eidx, gval, y + YSIZE);
  k_moe_gemm<<<dim3(24, 32), 256, 0, stream>>>(xb, weight, eidx, gval, cbuf, y);
}

// Round 2
// 191.860 us; speedup vs baseline: 1.5676x; 1.5676x over previous
//
#include <hip/hip_runtime.h>
#include <hip/hip_bf16.h>
#include <stdint.h>

#define B_ 32
#define S_ 512
#define D_ 768
#define O_ 768
#define E_ 8
#define YSIZE (B_ * S_ * O_)   // 12582912
#define BK 32

typedef __attribute__((ext_vector_type(8))) short bf16x8;
typedef __attribute__((ext_vector_type(4))) float f32x4;

static __device__ __forceinline__ unsigned short f2bf(float f) {
  union { float f; uint32_t u; } v; v.f = f;
  uint32_t u = v.u;
  uint32_t r = u + 0x7fff + ((u >> 16) & 1);   // RNE
  return (unsigned short)(r >> 16);
}

static __device__ __forceinline__ void async_load16(const void* g, void* l) {
  __builtin_amdgcn_global_load_lds(
      (const __attribute__((address_space(1))) void*)g,
      (__attribute__((address_space(3))) void*)l, 16, 0, 0);
}

// ---------------- Kernel 1: pool partial sums + x -> bf16 ----------------
// grid (3, 32, 4), block 256. Reads all of x once (coalesced), writes bf16 x
// and per-(chunk,b,d) partial sums.
__global__ void k_pool_convert(const float* __restrict__ x,
                               unsigned short* __restrict__ xb,
                               float* __restrict__ psum) {
  int d  = blockIdx.x * 256 + threadIdx.x;   // 0..767
  int b  = blockIdx.y;
  int sc = blockIdx.z;                        // 0..3, 128 s each
  const float* xp = x + ((size_t)(b * S_ + sc * 128)) * D_ + d;
  unsigned short* op = xb + ((size_t)(b * S_ + sc * 128)) * D_ + d;
  float sum = 0.f;
  #pragma unroll 8
  for (int s = 0; s < 128; ++s) {
    float v = xp[(size_t)s * D_];
    sum += v;
    op[(size_t)s * D_] = f2bf(v);
  }
  psum[(sc * B_ + b) * D_ + d] = sum;
}

// ---------------- Kernel 2a: logits + top-2 + softmax (one block per b) ----
__global__ __launch_bounds__(256) void k_logits(
    const float* __restrict__ psum, const float* __restrict__ w_gate,
    float* __restrict__ gates, int* __restrict__ eidx,
    float* __restrict__ gval) {
  int b = blockIdx.x;
  int tid = threadIdx.x;
  float acc[E_];
  #pragma unroll
  for (int e = 0; e < E_; ++e) acc[e] = 0.f;

  for (int d = tid; d < D_; d += 256) {
    float pooled = (psum[b * D_ + d] + psum[(B_ + b) * D_ + d] +
                    psum[(2 * B_ + b) * D_ + d] + psum[(3 * B_ + b) * D_ + d]) *
                   (1.0f / (float)S_);
    const float* wg = w_gate + d * E_;
    #pragma unroll
    for (int e = 0; e < E_; ++e) acc[e] += pooled * wg[e];
  }
  // wave butterfly reduce (64 lanes)
  #pragma unroll
  for (int off = 32; off > 0; off >>= 1) {
    #pragma unroll
    for (int e = 0; e < E_; ++e) acc[e] += __shfl_down(acc[e], off, 64);
  }
  __shared__ float part[4][E_];
  if ((tid & 63) == 0) {
    #pragma unroll
    for (int e = 0; e < E_; ++e) part[tid >> 6][e] = acc[e];
  }
  __syncthreads();
  if (tid == 0) {
    float lg[E_];
    #pragma unroll
    for (int e = 0; e < E_; ++e)
      lg[e] = part[0][e] + part[1][e] + part[2][e] + part[3][e];
    int i0 = 0; float v0 = lg[0];
    #pragma unroll
    for (int e = 1; e < E_; ++e) { if (lg[e] > v0) { v0 = lg[e]; i0 = e; } }
    int i1 = -1; float v1 = -1e30f;
    #pragma unroll
    for (int e = 0; e < E_; ++e) {
      if (e == i0) continue;
      if (lg[e] > v1) { v1 = lg[e]; i1 = e; }
    }
    float m  = fmaxf(v0, v1);
    float x0 = expf(v0 - m), x1 = expf(v1 - m);
    float s  = x0 + x1;
    float g0 = x0 / s, g1 = x1 / s;
    #pragma unroll
    for (int e = 0; e < E_; ++e)
      gates[b * E_ + e] = (e == i0) ? g0 : ((e == i1) ? g1 : 0.f);
    eidx[b] = i0; eidx[B_ + b] = i1;
    gval[b] = g0; gval[B_ + b] = g1;
  }
}

// ---------------- Kernel 2b: aux loss (tiny) ----------------
__global__ void k_loss(const float* __restrict__ gates,
                       float* __restrict__ loss_out) {
  int tid = threadIdx.x;
  __shared__ float imp[E_], loadv[E_];
  if (tid < E_) {
    float s = 0.f, c = 0.f;
    for (int b = 0; b < B_; ++b) {
      float g = gates[b * E_ + tid];
      s += g;
      c += (g > 0.f) ? 1.f : 0.f;
    }
    imp[tid] = s; loadv[tid] = c;
  }
  __syncthreads();
  if (tid == 0) {
    double mi = 0, ml = 0;
    for (int e = 0; e < E_; ++e) { mi += imp[e]; ml += loadv[e]; }
    mi /= E_; ml /= E_;
    double vi = 0, vl = 0;
    for (int e = 0; e < E_; ++e) {
      double di = imp[e] - mi, dl = loadv[e] - ml;
      vi += di * di; vl += dl * dl;
    }
    vi /= (E_ - 1); vl /= (E_ - 1);
    double cvi = vi / (mi * mi + 1e-10);
    double cvl = vl / (ml * ml + 1e-10);
    loss_out[0] = (float)((cvi + cvl) * 0.01);
  }
}

// ---------------- Kernel 3: batched GEMM y[b] = x[b] @ Wc[b]^T + cb[b] ----
// 128x128 tile, BK=32, 4 waves (2x2), each wave 64x64 (4x4 of 16x16x32 MFMA).
// A (bf16 x) staged via global_load_lds width=16; B combined on the fly from
// two fp32 expert weights (L2/L3-resident), packed to bf16 in LDS.
// Bias combined in the epilogue directly from `bias`.
__global__ __launch_bounds__(256) void k_moe_gemm(
    const unsigned short* __restrict__ xb, const float* __restrict__ weight,
    const int* __restrict__ eidx, const float* __restrict__ gval,
    const float* __restrict__ bias, float* __restrict__ y) {
  __shared__ unsigned short Alds[128 * BK];  // 8 KB
  __shared__ unsigned short Blds[128 * BK];  // 8 KB

  int b    = blockIdx.y;
  int tile = blockIdx.x;
  int st = tile & 3;          // S tile 0..3
  int ot = tile >> 2;         // O tile 0..5
  int s0 = st * 128, o0 = ot * 128;

  int tid  = threadIdx.x;
  int wave = tid >> 6, lane = tid & 63;
  int wm = wave & 1, wn = wave >> 1;

  int   e0 = eidx[b], e1 = eidx[B_ + b];
  float g0 = gval[b], g1 = gval[B_ + b];

  const unsigned short* Abase = xb + ((size_t)(b * S_ + s0)) * D_;
  const float* W0 = weight + (size_t)e0 * O_ * D_ + (size_t)o0 * D_;
  const float* W1 = weight + (size_t)e1 * O_ * D_ + (size_t)o0 * D_;

  int brow  = tid >> 1;   // 0..127
  int bhalf = tid & 1;    // k sub-offset 0/16

  f32x4 acc[4][4];
  #pragma unroll
  for (int i = 0; i < 4; ++i)
    #pragma unroll
    for (int j = 0; j < 4; ++j) acc[i][j] = (f32x4){0.f, 0.f, 0.f, 0.f};

  int a_chunk0 = wave * 2;
  int a_r = lane >> 2;        // row within 16-row chunk
  int a_c = (lane & 3) * 8;   // col element (8 bf16 = 16B)

  for (int kk = 0; kk < D_; kk += BK) {
    __syncthreads();
    // --- A: async global->LDS, 2x 1KB chunks per wave (row-major 128x32) ---
    #pragma unroll
    for (int j = 0; j < 2; ++j) {
      int chunk = a_chunk0 + j;
      const unsigned short* src =
          Abase + (size_t)(chunk * 16 + a_r) * D_ + kk + a_c;
      async_load16(src, Alds + chunk * 512);
    }
    // --- B: load fp32 from both experts, combine, pack bf16, ds_write ---
    {
      const float* p0 = W0 + (size_t)brow * D_ + kk + bhalf * 16;
      const float* p1 = W1 + (size_t)brow * D_ + kk + bhalf * 16;
      uint32_t pk[8];
      #pragma unroll
      for (int i = 0; i < 4; ++i) {
        float4 u0 = ((const float4*)p0)[i];
        float4 u1 = ((const float4*)p1)[i];
        float c0 = g0 * u0.x + g1 * u1.x;
        float c1 = g0 * u0.y + g1 * u1.y;
        float c2 = g0 * u0.z + g1 * u1.z;
        float c3 = g0 * u0.w + g1 * u1.w;
        pk[i * 2 + 0] = (uint32_t)f2bf(c0) | ((uint32_t)f2bf(c1) << 16);
        pk[i * 2 + 1] = (uint32_t)f2bf(c2) | ((uint32_t)f2bf(c3) << 16);
      }
      uint32_t* dst = (uint32_t*)(Blds + brow * 32 + bhalf * 16);
      ((uint4*)dst)[0] = make_uint4(pk[0], pk[1], pk[2], pk[3]);
      ((uint4*)dst)[1] = make_uint4(pk[4], pk[5], pk[6], pk[7]);
    }
    __syncthreads();   // compiler drains vmcnt(0) here -> A chunks landed

    // --- fragments + MFMA ---
    bf16x8 af[4], bfr[4];
    int koff = (lane >> 4) * 8;
    int r16  = lane & 15;
    #pragma unroll
    for (int mi = 0; mi < 4; ++mi)
      af[mi] = *(const bf16x8*)(Alds + (wm * 64 + mi * 16 + r16) * BK + koff);
    #pragma unroll
    for (int ni = 0; ni < 4; ++ni)
      bfr[ni] = *(const bf16x8*)(Blds + (wn * 64 + ni * 16 + r16) * BK + koff);
    #pragma unroll
    for (int mi = 0; mi < 4; ++mi)
      #pragma unroll
      for (int ni = 0; ni < 4; ++ni)
        acc[mi][ni] = __builtin_amdgcn_mfma_f32_16x16x32_bf16(
            af[mi], bfr[ni], acc[mi][ni], 0, 0, 0);
  }

  // --- epilogue: y = acc + g0*bias[e0] + g1*bias[e1] ---
  float* Y = y + ((size_t)(b * S_ + s0)) * O_ + o0;
  int col   = lane & 15;
  int rquad = (lane >> 4) * 4;
  #pragma unroll
  for (int ni = 0; ni < 4; ++ni) {
    int n = wn * 64 + ni * 16 + col;
    float cbv = g0 * bias[e0 * O_ + o0 + n] + g1 * bias[e1 * O_ + o0 + n];
    #pragma unroll
    for (int mi = 0; mi < 4; ++mi) {
      #pragma unroll
      for (int r = 0; r < 4; ++r) {
        int m = wm * 64 + mi * 16 + rquad + r;
        Y[(size_t)m * O_ + n] = acc[mi][ni][r] + cbv;
      }
    }
  }
}

// ---------------- launcher ----------------
// ws layout (bytes):
//   [0,           393216)  psum   float[4*32*768]
//   [393216,      394240)  gates  float[32*8]
//   [394240,      394496)  eidx   int[64]   (e0[32], e1[32])
//   [394496,      394752)  gval   float[64] (g0[32], g1[32])
//   [524288,    25690112)  x_bf16 ushort[32*512*768]
// total ws needed: ~25.7 MB
extern "C" void kernel_launch(void* const* d_in, const int* in_sizes, int n_in,
                              void* d_out, int out_size, void* d_ws, size_t ws_size,
                              hipStream_t stream) {
  const float* x      = (const float*)d_in[0];
  const float* w_gate = (const float*)d_in[1];
  const float* weight = (const float*)d_in[2];
  const float* bias   = (const float*)d_in[3];
  float* y = (float*)d_out;

  float* psum  = (float*)d_ws;
  float* gates = psum + 4 * B_ * D_;
  int*   eidx  = (int*)(gates + B_ * E_);
  float* gval  = (float*)(eidx + 64);
  unsigned short* xb = (unsigned short*)((char*)d_ws + 524288);

  k_pool_convert<<<dim3(3, 32, 4), 256, 0, stream>>>(x, xb, psum);
  k_logits<<<32, 256, 0, stream>>>(psum, w_gate, gates, eidx, gval);
  k_loss<<<1, 64, 0, stream>>>(gates, y + YSIZE);
  k_moe_gemm<<<dim3(24, 32), 256, 0, stream>>>(xb, weight, eidx, gval, bias, y);
}

// Round 3
// 181.177 us; speedup vs baseline: 1.6601x; 1.0590x over previous
//
#include <hip/hip_runtime.h>
#include <hip/hip_bf16.h>
#include <stdint.h>

#define B_ 32
#define S_ 512
#define D_ 768
#define O_ 768
#define E_ 8
#define YSIZE (B_ * S_ * O_)   // 12582912
#define BK 32
#define WSLICE (O_ * D_)       // 589824 elements per expert / per-b combined slice

typedef __attribute__((ext_vector_type(8))) short bf16x8;
typedef __attribute__((ext_vector_type(4))) float f32x4;

static __device__ __forceinline__ unsigned short f2bf(float f) {
  union { float f; uint32_t u; } v; v.f = f;
  uint32_t u = v.u;
  uint32_t r = u + 0x7fff + ((u >> 16) & 1);   // RNE
  return (unsigned short)(r >> 16);
}

static __device__ __forceinline__ void async_load16(const void* g, void* l) {
  __builtin_amdgcn_global_load_lds(
      (const __attribute__((address_space(1))) void*)g,
      (__attribute__((address_space(3))) void*)l, 16, 0, 0);
}

// ---------------- Kernel 1: pool partial sums + x -> bf16 ----------------
// grid (3, 32, 16), block 256 -> 1536 blocks (6/CU), 32 s-rows per block.
__global__ void k_pool_convert(const float* __restrict__ x,
                               unsigned short* __restrict__ xb,
                               float* __restrict__ psum) {
  int d  = blockIdx.x * 256 + threadIdx.x;   // 0..767
  int b  = blockIdx.y;
  int sc = blockIdx.z;                        // 0..15, 32 s each
  const float* xp = x + ((size_t)(b * S_ + sc * 32)) * D_ + d;
  unsigned short* op = xb + ((size_t)(b * S_ + sc * 32)) * D_ + d;
  float sum = 0.f;
  #pragma unroll 8
  for (int s = 0; s < 32; ++s) {
    float v = xp[(size_t)s * D_];
    sum += v;
    op[(size_t)s * D_] = f2bf(v);
  }
  psum[(sc * B_ + b) * D_ + d] = sum;
}

// ---------------- Kernel 2a: logits + top-2 + softmax (one block per b) ----
__global__ __launch_bounds__(256) void k_logits(
    const float* __restrict__ psum, const float* __restrict__ w_gate,
    float* __restrict__ gates, int* __restrict__ eidx,
    float* __restrict__ gval) {
  int b = blockIdx.x;
  int tid = threadIdx.x;
  float acc[E_];
  #pragma unroll
  for (int e = 0; e < E_; ++e) acc[e] = 0.f;

  for (int d = tid; d < D_; d += 256) {
    float p = 0.f;
    #pragma unroll
    for (int c = 0; c < 16; ++c) p += psum[(c * B_ + b) * D_ + d];
    p *= (1.0f / (float)S_);
    const float* wg = w_gate + d * E_;
    #pragma unroll
    for (int e = 0; e < E_; ++e) acc[e] += p * wg[e];
  }
  #pragma unroll
  for (int off = 32; off > 0; off >>= 1) {
    #pragma unroll
    for (int e = 0; e < E_; ++e) acc[e] += __shfl_down(acc[e], off, 64);
  }
  __shared__ float part[4][E_];
  if ((tid & 63) == 0) {
    #pragma unroll
    for (int e = 0; e < E_; ++e) part[tid >> 6][e] = acc[e];
  }
  __syncthreads();
  if (tid == 0) {
    float lg[E_];
    #pragma unroll
    for (int e = 0; e < E_; ++e)
      lg[e] = part[0][e] + part[1][e] + part[2][e] + part[3][e];
    int i0 = 0; float v0 = lg[0];
    #pragma unroll
    for (int e = 1; e < E_; ++e) { if (lg[e] > v0) { v0 = lg[e]; i0 = e; } }
    int i1 = -1; float v1 = -1e30f;
    #pragma unroll
    for (int e = 0; e < E_; ++e) {
      if (e == i0) continue;
      if (lg[e] > v1) { v1 = lg[e]; i1 = e; }
    }
    float m  = fmaxf(v0, v1);
    float x0 = expf(v0 - m), x1 = expf(v1 - m);
    float s  = x0 + x1;
    float g0 = x0 / s, g1 = x1 / s;
    #pragma unroll
    for (int e = 0; e < E_; ++e)
      gates[b * E_ + e] = (e == i0) ? g0 : ((e == i1) ? g1 : 0.f);
    eidx[b] = i0; eidx[B_ + b] = i1;
    gval[b] = g0; gval[B_ + b] = g1;
  }
}

// ---------------- Kernel 2b: aux loss (tiny) ----------------
__global__ void k_loss(const float* __restrict__ gates,
                       float* __restrict__ loss_out) {
  int tid = threadIdx.x;
  __shared__ float imp[E_], loadv[E_];
  if (tid < E_) {
    float s = 0.f, c = 0.f;
    for (int b = 0; b < B_; ++b) {
      float g = gates[b * E_ + tid];
      s += g;
      c += (g > 0.f) ? 1.f : 0.f;
    }
    imp[tid] = s; loadv[tid] = c;
  }
  __syncthreads();
  if (tid == 0) {
    double mi = 0, ml = 0;
    for (int e = 0; e < E_; ++e) { mi += imp[e]; ml += loadv[e]; }
    mi /= E_; ml /= E_;
    double vi = 0, vl = 0;
    for (int e = 0; e < E_; ++e) {
      double di = imp[e] - mi, dl = loadv[e] - ml;
      vi += di * di; vl += dl * dl;
    }
    vi /= (E_ - 1); vl /= (E_ - 1);
    double cvi = vi / (mi * mi + 1e-10);
    double cvl = vl / (ml * ml + 1e-10);
    loss_out[0] = (float)((cvi + cvl) * 0.01);
  }
}

// ---------------- Kernel 2c: combined weights Wc[b] = sum_e gates[b][e]W[e] -
// grid (288), block 256. Each thread owns 8 consecutive elements of the
// (o,d) slice; reads all 8 experts once (each weight elem read exactly once
// from HBM), writes 32 b-slices. Dense 8-FMA dot avoids indexed reg gather.
__global__ __launch_bounds__(256) void k_combine(
    const float* __restrict__ weight, const float* __restrict__ gates,
    unsigned short* __restrict__ wc) {
  __shared__ float gsh[B_][E_];
  int tid = threadIdx.x;
  if (tid < B_ * E_) ((float*)gsh)[tid] = gates[tid];
  __syncthreads();

  size_t i = (size_t)blockIdx.x * 2048 + tid * 8;
  float v[E_][8];
  #pragma unroll
  for (int e = 0; e < E_; ++e) {
    float4 u0 = *(const float4*)(weight + (size_t)e * WSLICE + i);
    float4 u1 = *(const float4*)(weight + (size_t)e * WSLICE + i + 4);
    v[e][0] = u0.x; v[e][1] = u0.y; v[e][2] = u0.z; v[e][3] = u0.w;
    v[e][4] = u1.x; v[e][5] = u1.y; v[e][6] = u1.z; v[e][7] = u1.w;
  }
  for (int b = 0; b < B_; ++b) {
    float c[8];
    #pragma unroll
    for (int j = 0; j < 8; ++j) c[j] = 0.f;
    #pragma unroll
    for (int e = 0; e < E_; ++e) {
      float g = gsh[b][e];
      #pragma unroll
      for (int j = 0; j < 8; ++j) c[j] += g * v[e][j];
    }
    uint32_t pk[4];
    #pragma unroll
    for (int j = 0; j < 4; ++j)
      pk[j] = (uint32_t)f2bf(c[2 * j]) | ((uint32_t)f2bf(c[2 * j + 1]) << 16);
    *(uint4*)(wc + (size_t)b * WSLICE + i) = make_uint4(pk[0], pk[1], pk[2], pk[3]);
  }
}

// ---------------- Kernel 3: batched GEMM y[b] = x[b] @ Wc[b]^T + bias ------
// m97 structure: 128x128 tile, BK=32, 4 waves (2x2), 4x4 of 16x16x32 MFMA,
// both A and B staged via global_load_lds width=16.
__global__ __launch_bounds__(256) void k_moe_gemm(
    const unsigned short* __restrict__ xb, const unsigned short* __restrict__ wc,
    const int* __restrict__ eidx, const float* __restrict__ gval,
    const float* __restrict__ bias, float* __restrict__ y) {
  __shared__ unsigned short Alds[128 * BK];  // 8 KB
  __shared__ unsigned short Blds[128 * BK];  // 8 KB

  int b    = blockIdx.y;
  int tile = blockIdx.x;
  int st = tile & 3;          // S tile 0..3
  int ot = tile >> 2;         // O tile 0..5
  int s0 = st * 128, o0 = ot * 128;

  int tid  = threadIdx.x;
  int wave = tid >> 6, lane = tid & 63;
  int wm = wave & 1, wn = wave >> 1;

  const unsigned short* Abase = xb + ((size_t)(b * S_ + s0)) * D_;
  const unsigned short* Bbase = wc + (size_t)b * WSLICE + (size_t)o0 * D_;

  f32x4 acc[4][4];
  #pragma unroll
  for (int i = 0; i < 4; ++i)
    #pragma unroll
    for (int j = 0; j < 4; ++j) acc[i][j] = (f32x4){0.f, 0.f, 0.f, 0.f};

  int a_chunk0 = wave * 2;
  int a_r = lane >> 2;        // row within 16-row chunk
  int a_c = (lane & 3) * 8;   // col element (8 bf16 = 16B)

  for (int kk = 0; kk < D_; kk += BK) {
    __syncthreads();
    #pragma unroll
    for (int j = 0; j < 2; ++j) {
      int chunk = a_chunk0 + j;
      const unsigned short* srcA =
          Abase + (size_t)(chunk * 16 + a_r) * D_ + kk + a_c;
      async_load16(srcA, Alds + chunk * 512);
      const unsigned short* srcB =
          Bbase + (size_t)(chunk * 16 + a_r) * D_ + kk + a_c;
      async_load16(srcB, Blds + chunk * 512);
    }
    __syncthreads();   // vmcnt(0) drain -> all chunks landed

    bf16x8 af[4], bfr[4];
    int koff = (lane >> 4) * 8;
    int r16  = lane & 15;
    #pragma unroll
    for (int mi = 0; mi < 4; ++mi)
      af[mi] = *(const bf16x8*)(Alds + (wm * 64 + mi * 16 + r16) * BK + koff);
    #pragma unroll
    for (int ni = 0; ni < 4; ++ni)
      bfr[ni] = *(const bf16x8*)(Blds + (wn * 64 + ni * 16 + r16) * BK + koff);
    #pragma unroll
    for (int mi = 0; mi < 4; ++mi)
      #pragma unroll
      for (int ni = 0; ni < 4; ++ni)
        acc[mi][ni] = __builtin_amdgcn_mfma_f32_16x16x32_bf16(
            af[mi], bfr[ni], acc[mi][ni], 0, 0, 0);
  }

  // --- epilogue: y = acc + g0*bias[e0] + g1*bias[e1] ---
  int   e0 = eidx[b], e1 = eidx[B_ + b];
  float g0 = gval[b], g1 = gval[B_ + b];
  float* Y = y + ((size_t)(b * S_ + s0)) * O_ + o0;
  int col   = lane & 15;
  int rquad = (lane >> 4) * 4;
  #pragma unroll
  for (int ni = 0; ni < 4; ++ni) {
    int n = wn * 64 + ni * 16 + col;
    float cbv = g0 * bias[e0 * O_ + o0 + n] + g1 * bias[e1 * O_ + o0 + n];
    #pragma unroll
    for (int mi = 0; mi < 4; ++mi) {
      #pragma unroll
      for (int r = 0; r < 4; ++r) {
        int m = wm * 64 + mi * 16 + rquad + r;
        Y[(size_t)m * O_ + n] = acc[mi][ni][r] + cbv;
      }
    }
  }
}

// ---------------- launcher ----------------
// ws layout (bytes):
//   [0,        1572864)  psum   float[16*32*768]
//   [1572864,  1573888)  gates  float[32*8]
//   [1573888,  1574144)  eidx   int[64]
//   [1574144,  1574400)  gval   float[64]
//   [2097152, 27262976)  x_bf16 ushort[32*512*768]   (25.2 MB)
//   [27262976,65011712)  wc     ushort[32*768*768]   (37.7 MB)
extern "C" void kernel_launch(void* const* d_in, const int* in_sizes, int n_in,
                              void* d_out, int out_size, void* d_ws, size_t ws_size,
                              hipStream_t stream) {
  const float* x      = (const float*)d_in[0];
  const float* w_gate = (const float*)d_in[1];
  const float* weight = (const float*)d_in[2];
  const float* bias   = (const float*)d_in[3];
  float* y = (float*)d_out;

  float* psum  = (float*)d_ws;
  float* gates = (float*)((char*)d_ws + 1572864);
  int*   eidx  = (int*)((char*)d_ws + 1573888);
  float* gval  = (float*)((char*)d_ws + 1574144);
  unsigned short* xb = (unsigned short*)((char*)d_ws + 2097152);
  unsigned short* wc = (unsigned short*)((char*)d_ws + 27262976);

  k_pool_convert<<<dim3(3, 32, 16), 256, 0, stream>>>(x, xb, psum);
  k_logits<<<32, 256, 0, stream>>>(psum, w_gate, gates, eidx, gval);
  k_loss<<<1, 64, 0, stream>>>(gates, y + YSIZE);
  k_combine<<<288, 256, 0, stream>>>(weight, gates, wc);
  k_moe_gemm<<<dim3(24, 32), 256, 0, stream>>>(xb, wc, eidx, gval, bias, y);
}

// Round 4
// 171.899 us; speedup vs baseline: 1.7497x; 1.0540x over previous
//
#include <hip/hip_runtime.h>
#include <hip/hip_bf16.h>
#include <stdint.h>

#define B_ 32
#define S_ 512
#define D_ 768
#define O_ 768
#define E_ 8
#define YSIZE (B_ * S_ * O_)   // 12582912
#define BK 32
#define WSLICE (O_ * D_)       // 589824 elements per expert / per-b combined slice

typedef __attribute__((ext_vector_type(8))) short bf16x8;
typedef __attribute__((ext_vector_type(4))) float f32x4;

static __device__ __forceinline__ unsigned short f2bf(float f) {
  union { float f; uint32_t u; } v; v.f = f;
  uint32_t u = v.u;
  uint32_t r = u + 0x7fff + ((u >> 16) & 1);   // RNE
  return (unsigned short)(r >> 16);
}

static __device__ __forceinline__ void async_load16(const void* g, void* l) {
  __builtin_amdgcn_global_load_lds(
      (const __attribute__((address_space(1))) void*)g,
      (__attribute__((address_space(3))) void*)l, 16, 0, 0);
}

// ---------------- Kernel 1: pool partial sums + x -> bf16 ----------------
// grid (32, 16), block 192 (3 waves): thread t owns d = 4t..4t+3 (float4).
// 16 B/lane coalesced loads; 8 B/lane stores; 32 s-rows per block.
__global__ __launch_bounds__(192) void k_pool_convert(
    const float* __restrict__ x, unsigned short* __restrict__ xb,
    float* __restrict__ psum) {
  int t  = threadIdx.x;          // 0..191
  int b  = blockIdx.x;
  int sc = blockIdx.y;           // 0..15, 32 s-rows each
  size_t rowbase = (size_t)(b * S_ + sc * 32) * D_;
  const float* xp = x + rowbase + 4 * t;
  unsigned short* op = xb + rowbase + 4 * t;
  float4 sum = {0.f, 0.f, 0.f, 0.f};
  #pragma unroll 8
  for (int s = 0; s < 32; ++s) {
    float4 v = *(const float4*)(xp + (size_t)s * D_);
    sum.x += v.x; sum.y += v.y; sum.z += v.z; sum.w += v.w;
    ushort4 o;
    o.x = f2bf(v.x); o.y = f2bf(v.y); o.z = f2bf(v.z); o.w = f2bf(v.w);
    *(ushort4*)(op + (size_t)s * D_) = o;
  }
  *(float4*)(psum + (size_t)(sc * B_ + b) * D_ + 4 * t) = sum;
}

// ---------------- Kernel 2a: logits + top-2 + softmax (one block per b) ----
__global__ __launch_bounds__(256) void k_logits(
    const float* __restrict__ psum, const float* __restrict__ w_gate,
    float* __restrict__ gates, int* __restrict__ eidx,
    float* __restrict__ gval) {
  int b = blockIdx.x;
  int tid = threadIdx.x;
  float acc[E_];
  #pragma unroll
  for (int e = 0; e < E_; ++e) acc[e] = 0.f;

  for (int d = tid; d < D_; d += 256) {
    float p = 0.f;
    #pragma unroll
    for (int c = 0; c < 16; ++c) p += psum[(c * B_ + b) * D_ + d];
    p *= (1.0f / (float)S_);
    const float* wg = w_gate + d * E_;
    #pragma unroll
    for (int e = 0; e < E_; ++e) acc[e] += p * wg[e];
  }
  #pragma unroll
  for (int off = 32; off > 0; off >>= 1) {
    #pragma unroll
    for (int e = 0; e < E_; ++e) acc[e] += __shfl_down(acc[e], off, 64);
  }
  __shared__ float part[4][E_];
  if ((tid & 63) == 0) {
    #pragma unroll
    for (int e = 0; e < E_; ++e) part[tid >> 6][e] = acc[e];
  }
  __syncthreads();
  if (tid == 0) {
    float lg[E_];
    #pragma unroll
    for (int e = 0; e < E_; ++e)
      lg[e] = part[0][e] + part[1][e] + part[2][e] + part[3][e];
    int i0 = 0; float v0 = lg[0];
    #pragma unroll
    for (int e = 1; e < E_; ++e) { if (lg[e] > v0) { v0 = lg[e]; i0 = e; } }
    int i1 = -1; float v1 = -1e30f;
    #pragma unroll
    for (int e = 0; e < E_; ++e) {
      if (e == i0) continue;
      if (lg[e] > v1) { v1 = lg[e]; i1 = e; }
    }
    float m  = fmaxf(v0, v1);
    float x0 = expf(v0 - m), x1 = expf(v1 - m);
    float s  = x0 + x1;
    float g0 = x0 / s, g1 = x1 / s;
    #pragma unroll
    for (int e = 0; e < E_; ++e)
      gates[b * E_ + e] = (e == i0) ? g0 : ((e == i1) ? g1 : 0.f);
    eidx[b] = i0; eidx[B_ + b] = i1;
    gval[b] = g0; gval[B_ + b] = g1;
  }
}

// ---------------- Kernel 2c: combined weights + fused aux loss ------------
// grid (288, 4), block 256. blockIdx.x tiles the (o,d) slice in 2048-elem
// chunks (8 per thread); blockIdx.y picks a group of 8 batches. Weight is
// fetched 4x but L3-resident; write-bound overall. Loss computed serially by
// thread 0 of block (0,0) from the LDS-staged gates.
__global__ __launch_bounds__(256) void k_combine(
    const float* __restrict__ weight, const float* __restrict__ gates,
    unsigned short* __restrict__ wc, float* __restrict__ loss_out) {
  __shared__ float gsh[B_][E_];
  int tid = threadIdx.x;
  if (tid < B_ * E_) ((float*)gsh)[tid] = gates[tid];
  __syncthreads();

  if (blockIdx.x == 0 && blockIdx.y == 0 && tid == 0) {
    double mi = 0, ml = 0;
    float imp[E_], ldv[E_];
    #pragma unroll
    for (int e = 0; e < E_; ++e) {
      float s = 0.f, c = 0.f;
      for (int b = 0; b < B_; ++b) {
        float g = gsh[b][e];
        s += g; c += (g > 0.f) ? 1.f : 0.f;
      }
      imp[e] = s; ldv[e] = c;
      mi += s; ml += c;
    }
    mi /= E_; ml /= E_;
    double vi = 0, vl = 0;
    #pragma unroll
    for (int e = 0; e < E_; ++e) {
      double di = imp[e] - mi, dl = ldv[e] - ml;
      vi += di * di; vl += dl * dl;
    }
    vi /= (E_ - 1); vl /= (E_ - 1);
    loss_out[0] = (float)((vi / (mi * mi + 1e-10) + vl / (ml * ml + 1e-10)) * 0.01);
  }

  size_t i = (size_t)blockIdx.x * 2048 + tid * 8;
  int b0 = blockIdx.y * 8;
  float v[E_][8];
  #pragma unroll
  for (int e = 0; e < E_; ++e) {
    float4 u0 = *(const float4*)(weight + (size_t)e * WSLICE + i);
    float4 u1 = *(const float4*)(weight + (size_t)e * WSLICE + i + 4);
    v[e][0] = u0.x; v[e][1] = u0.y; v[e][2] = u0.z; v[e][3] = u0.w;
    v[e][4] = u1.x; v[e][5] = u1.y; v[e][6] = u1.z; v[e][7] = u1.w;
  }
  #pragma unroll
  for (int bb = 0; bb < 8; ++bb) {
    int b = b0 + bb;
    float c[8];
    #pragma unroll
    for (int j = 0; j < 8; ++j) c[j] = 0.f;
    #pragma unroll
    for (int e = 0; e < E_; ++e) {
      float g = gsh[b][e];
      #pragma unroll
      for (int j = 0; j < 8; ++j) c[j] += g * v[e][j];
    }
    uint32_t pk[4];
    #pragma unroll
    for (int j = 0; j < 4; ++j)
      pk[j] = (uint32_t)f2bf(c[2 * j]) | ((uint32_t)f2bf(c[2 * j + 1]) << 16);
    *(uint4*)(wc + (size_t)b * WSLICE + i) = make_uint4(pk[0], pk[1], pk[2], pk[3]);
  }
}

// ---------------- Kernel 3: batched GEMM y[b] = x[b] @ Wc[b]^T + bias ------
// m97 structure: 128x128 tile, BK=32, 4 waves (2x2), 4x4 of 16x16x32 MFMA,
// both A and B staged via global_load_lds width=16. (Unchanged from R3.)
__global__ __launch_bounds__(256) void k_moe_gemm(
    const unsigned short* __restrict__ xb, const unsigned short* __restrict__ wc,
    const int* __restrict__ eidx, const float* __restrict__ gval,
    const float* __restrict__ bias, float* __restrict__ y) {
  __shared__ unsigned short Alds[128 * BK];  // 8 KB
  __shared__ unsigned short Blds[128 * BK];  // 8 KB

  int b    = blockIdx.y;
  int tile = blockIdx.x;
  int st = tile & 3;          // S tile 0..3
  int ot = tile >> 2;         // O tile 0..5
  int s0 = st * 128, o0 = ot * 128;

  int tid  = threadIdx.x;
  int wave = tid >> 6, lane = tid & 63;
  int wm = wave & 1, wn = wave >> 1;

  const unsigned short* Abase = xb + ((size_t)(b * S_ + s0)) * D_;
  const unsigned short* Bbase = wc + (size_t)b * WSLICE + (size_t)o0 * D_;

  f32x4 acc[4][4];
  #pragma unroll
  for (int i = 0; i < 4; ++i)
    #pragma unroll
    for (int j = 0; j < 4; ++j) acc[i][j] = (f32x4){0.f, 0.f, 0.f, 0.f};

  int a_chunk0 = wave * 2;
  int a_r = lane >> 2;        // row within 16-row chunk
  int a_c = (lane & 3) * 8;   // col element (8 bf16 = 16B)

  for (int kk = 0; kk < D_; kk += BK) {
    __syncthreads();
    #pragma unroll
    for (int j = 0; j < 2; ++j) {
      int chunk = a_chunk0 + j;
      const unsigned short* srcA =
          Abase + (size_t)(chunk * 16 + a_r) * D_ + kk + a_c;
      async_load16(srcA, Alds + chunk * 512);
      const unsigned short* srcB =
          Bbase + (size_t)(chunk * 16 + a_r) * D_ + kk + a_c;
      async_load16(srcB, Blds + chunk * 512);
    }
    __syncthreads();   // vmcnt(0) drain -> all chunks landed

    bf16x8 af[4], bfr[4];
    int koff = (lane >> 4) * 8;
    int r16  = lane & 15;
    #pragma unroll
    for (int mi = 0; mi < 4; ++mi)
      af[mi] = *(const bf16x8*)(Alds + (wm * 64 + mi * 16 + r16) * BK + koff);
    #pragma unroll
    for (int ni = 0; ni < 4; ++ni)
      bfr[ni] = *(const bf16x8*)(Blds + (wn * 64 + ni * 16 + r16) * BK + koff);
    #pragma unroll
    for (int mi = 0; mi < 4; ++mi)
      #pragma unroll
      for (int ni = 0; ni < 4; ++ni)
        acc[mi][ni] = __builtin_amdgcn_mfma_f32_16x16x32_bf16(
            af[mi], bfr[ni], acc[mi][ni], 0, 0, 0);
  }

  // --- epilogue: y = acc + g0*bias[e0] + g1*bias[e1] ---
  int   e0 = eidx[b], e1 = eidx[B_ + b];
  float g0 = gval[b], g1 = gval[B_ + b];
  float* Y = y + ((size_t)(b * S_ + s0)) * O_ + o0;
  int col   = lane & 15;
  int rquad = (lane >> 4) * 4;
  #pragma unroll
  for (int ni = 0; ni < 4; ++ni) {
    int n = wn * 64 + ni * 16 + col;
    float cbv = g0 * bias[e0 * O_ + o0 + n] + g1 * bias[e1 * O_ + o0 + n];
    #pragma unroll
    for (int mi = 0; mi < 4; ++mi) {
      #pragma unroll
      for (int r = 0; r < 4; ++r) {
        int m = wm * 64 + mi * 16 + rquad + r;
        Y[(size_t)m * O_ + n] = acc[mi][ni][r] + cbv;
      }
    }
  }
}

// ---------------- launcher ----------------
// ws layout (bytes):
//   [0,        1572864)  psum   float[16*32*768]
//   [1572864,  1573888)  gates  float[32*8]
//   [1573888,  1574144)  eidx   int[64]
//   [1574144,  1574400)  gval   float[64]
//   [2097152, 27262976)  x_bf16 ushort[32*512*768]   (25.2 MB)
//   [27262976,65011712)  wc     ushort[32*768*768]   (37.7 MB)
extern "C" void kernel_launch(void* const* d_in, const int* in_sizes, int n_in,
                              void* d_out, int out_size, void* d_ws, size_t ws_size,
                              hipStream_t stream) {
  const float* x      = (const float*)d_in[0];
  const float* w_gate = (const float*)d_in[1];
  const float* weight = (const float*)d_in[2];
  const float* bias   = (const float*)d_in[3];
  float* y = (float*)d_out;

  float* psum  = (float*)d_ws;
  float* gates = (float*)((char*)d_ws + 1572864);
  int*   eidx  = (int*)((char*)d_ws + 1573888);
  float* gval  = (float*)((char*)d_ws + 1574144);
  unsigned short* xb = (unsigned short*)((char*)d_ws + 2097152);
  unsigned short* wc = (unsigned short*)((char*)d_ws + 27262976);

  k_pool_convert<<<dim3(32, 16), 192, 0, stream>>>(x, xb, psum);
  k_logits<<<32, 256, 0, stream>>>(psum, w_gate, gates, eidx, gval);
  k_combine<<<dim3(288, 4), 256, 0, stream>>>(weight, gates, wc, y + YSIZE);
  k_moe_gemm<<<dim3(24, 32), 256, 0, stream>>>(xb, wc, eidx, gval, bias, y);
}

// Round 5
// 161.850 us; speedup vs baseline: 1.8583x; 1.0621x over previous
//
#include <hip/hip_runtime.h>
#include <hip/hip_bf16.h>
#include <stdint.h>

#define B_ 32
#define S_ 512
#define D_ 768
#define O_ 768
#define E_ 8
#define YSIZE (B_ * S_ * O_)   // 12582912
#define BK 32
#define WSLICE (O_ * D_)       // 589824 elements per expert / per-b combined slice

typedef __attribute__((ext_vector_type(8))) short bf16x8;
typedef __attribute__((ext_vector_type(4))) float f32x4;

static __device__ __forceinline__ unsigned short f2bf(float f) {
  union { float f; uint32_t u; } v; v.f = f;
  uint32_t u = v.u;
  uint32_t r = u + 0x7fff + ((u >> 16) & 1);   // RNE
  return (unsigned short)(r >> 16);
}

static __device__ __forceinline__ void async_load16(const void* g, void* l) {
  __builtin_amdgcn_global_load_lds(
      (const __attribute__((address_space(1))) void*)g,
      (__attribute__((address_space(3))) void*)l, 16, 0, 0);
}

// ---------------- Kernel 1: pool partial sums + x -> bf16 ----------------
// grid (32, 16), block 192 (3 waves): thread t owns d = 4t..4t+3 (float4).
__global__ __launch_bounds__(192) void k_pool_convert(
    const float* __restrict__ x, unsigned short* __restrict__ xb,
    float* __restrict__ psum) {
  int t  = threadIdx.x;          // 0..191
  int b  = blockIdx.x;
  int sc = blockIdx.y;           // 0..15, 32 s-rows each
  size_t rowbase = (size_t)(b * S_ + sc * 32) * D_;
  const float* xp = x + rowbase + 4 * t;
  unsigned short* op = xb + rowbase + 4 * t;
  float4 sum = {0.f, 0.f, 0.f, 0.f};
  #pragma unroll 8
  for (int s = 0; s < 32; ++s) {
    float4 v = *(const float4*)(xp + (size_t)s * D_);
    sum.x += v.x; sum.y += v.y; sum.z += v.z; sum.w += v.w;
    ushort4 o;
    o.x = f2bf(v.x); o.y = f2bf(v.y); o.z = f2bf(v.z); o.w = f2bf(v.w);
    *(ushort4*)(op + (size_t)s * D_) = o;
  }
  *(float4*)(psum + (size_t)(sc * B_ + b) * D_ + 4 * t) = sum;
}

// ---------------- Kernel 2a: logits + top-2 + softmax (one block per b) ----
__global__ __launch_bounds__(256) void k_logits(
    const float* __restrict__ psum, const float* __restrict__ w_gate,
    float* __restrict__ gates, int* __restrict__ eidx,
    float* __restrict__ gval) {
  int b = blockIdx.x;
  int tid = threadIdx.x;
  float acc[E_];
  #pragma unroll
  for (int e = 0; e < E_; ++e) acc[e] = 0.f;

  for (int d = tid; d < D_; d += 256) {
    float p = 0.f;
    #pragma unroll
    for (int c = 0; c < 16; ++c) p += psum[(c * B_ + b) * D_ + d];
    p *= (1.0f / (float)S_);
    const float* wg = w_gate + d * E_;
    #pragma unroll
    for (int e = 0; e < E_; ++e) acc[e] += p * wg[e];
  }
  #pragma unroll
  for (int off = 32; off > 0; off >>= 1) {
    #pragma unroll
    for (int e = 0; e < E_; ++e) acc[e] += __shfl_down(acc[e], off, 64);
  }
  __shared__ float part[4][E_];
  if ((tid & 63) == 0) {
    #pragma unroll
    for (int e = 0; e < E_; ++e) part[tid >> 6][e] = acc[e];
  }
  __syncthreads();
  if (tid == 0) {
    float lg[E_];
    #pragma unroll
    for (int e = 0; e < E_; ++e)
      lg[e] = part[0][e] + part[1][e] + part[2][e] + part[3][e];
    int i0 = 0; float v0 = lg[0];
    #pragma unroll
    for (int e = 1; e < E_; ++e) { if (lg[e] > v0) { v0 = lg[e]; i0 = e; } }
    int i1 = -1; float v1 = -1e30f;
    #pragma unroll
    for (int e = 0; e < E_; ++e) {
      if (e == i0) continue;
      if (lg[e] > v1) { v1 = lg[e]; i1 = e; }
    }
    float m  = fmaxf(v0, v1);
    float x0 = expf(v0 - m), x1 = expf(v1 - m);
    float s  = x0 + x1;
    float g0 = x0 / s, g1 = x1 / s;
    #pragma unroll
    for (int e = 0; e < E_; ++e)
      gates[b * E_ + e] = (e == i0) ? g0 : ((e == i1) ? g1 : 0.f);
    eidx[b] = i0; eidx[B_ + b] = i1;
    gval[b] = g0; gval[B_ + b] = g1;
  }
}

// ---------------- Kernel 2c: combined weights + fused aux loss ------------
// grid (288, 4), block 256. Unchanged from R4.
__global__ __launch_bounds__(256) void k_combine(
    const float* __restrict__ weight, const float* __restrict__ gates,
    unsigned short* __restrict__ wc, float* __restrict__ loss_out) {
  __shared__ float gsh[B_][E_];
  int tid = threadIdx.x;
  if (tid < B_ * E_) ((float*)gsh)[tid] = gates[tid];
  __syncthreads();

  if (blockIdx.x == 0 && blockIdx.y == 0 && tid == 0) {
    double mi = 0, ml = 0;
    float imp[E_], ldv[E_];
    #pragma unroll
    for (int e = 0; e < E_; ++e) {
      float s = 0.f, c = 0.f;
      for (int b = 0; b < B_; ++b) {
        float g = gsh[b][e];
        s += g; c += (g > 0.f) ? 1.f : 0.f;
      }
      imp[e] = s; ldv[e] = c;
      mi += s; ml += c;
    }
    mi /= E_; ml /= E_;
    double vi = 0, vl = 0;
    #pragma unroll
    for (int e = 0; e < E_; ++e) {
      double di = imp[e] - mi, dl = ldv[e] - ml;
      vi += di * di; vl += dl * dl;
    }
    vi /= (E_ - 1); vl /= (E_ - 1);
    loss_out[0] = (float)((vi / (mi * mi + 1e-10) + vl / (ml * ml + 1e-10)) * 0.01);
  }

  size_t i = (size_t)blockIdx.x * 2048 + tid * 8;
  int b0 = blockIdx.y * 8;
  float v[E_][8];
  #pragma unroll
  for (int e = 0; e < E_; ++e) {
    float4 u0 = *(const float4*)(weight + (size_t)e * WSLICE + i);
    float4 u1 = *(const float4*)(weight + (size_t)e * WSLICE + i + 4);
    v[e][0] = u0.x; v[e][1] = u0.y; v[e][2] = u0.z; v[e][3] = u0.w;
    v[e][4] = u1.x; v[e][5] = u1.y; v[e][6] = u1.z; v[e][7] = u1.w;
  }
  #pragma unroll
  for (int bb = 0; bb < 8; ++bb) {
    int b = b0 + bb;
    float c[8];
    #pragma unroll
    for (int j = 0; j < 8; ++j) c[j] = 0.f;
    #pragma unroll
    for (int e = 0; e < E_; ++e) {
      float g = gsh[b][e];
      #pragma unroll
      for (int j = 0; j < 8; ++j) c[j] += g * v[e][j];
    }
    uint32_t pk[4];
    #pragma unroll
    for (int j = 0; j < 4; ++j)
      pk[j] = (uint32_t)f2bf(c[2 * j]) | ((uint32_t)f2bf(c[2 * j + 1]) << 16);
    *(uint4*)(wc + (size_t)b * WSLICE + i) = make_uint4(pk[0], pk[1], pk[2], pk[3]);
  }
}

// ---------------- Kernel 3: batched GEMM y[b] = x[b] @ Wc[b]^T + bias ------
// 128x128 tile, K-step = 64 via two BK=32 slabs (one barrier pair per 64 K),
// XCD-affine flat grid: all 24 tiles of batch b run on XCD b%8 so xb/wc
// re-reads hit that XCD's L2. 4 waves (2x2), 4x4(x2) of 16x16x32 MFMA.
__global__ __launch_bounds__(256, 3) void k_moe_gemm(
    const unsigned short* __restrict__ xb, const unsigned short* __restrict__ wc,
    const int* __restrict__ eidx, const float* __restrict__ gval,
    const float* __restrict__ bias, float* __restrict__ y) {
  __shared__ unsigned short Alds[2][128 * BK];  // 2 x 8 KB
  __shared__ unsigned short Blds[2][128 * BK];  // 2 x 8 KB

  // XCD-affine decode: blockId % 8 selects XCD (round-robin dispatch).
  int flat = blockIdx.x;          // 0..767
  int xcd  = flat & 7;
  int slot = flat >> 3;           // 0..95
  int b    = xcd + 8 * (slot / 24);
  int tile = slot % 24;
  int st = tile & 3;              // S tile 0..3
  int ot = tile >> 2;             // O tile 0..5
  int s0 = st * 128, o0 = ot * 128;

  int tid  = threadIdx.x;
  int wave = tid >> 6, lane = tid & 63;
  int wm = wave & 1, wn = wave >> 1;

  const unsigned short* Abase = xb + ((size_t)(b * S_ + s0)) * D_;
  const unsigned short* Bbase = wc + (size_t)b * WSLICE + (size_t)o0 * D_;

  f32x4 acc[4][4];
  #pragma unroll
  for (int i = 0; i < 4; ++i)
    #pragma unroll
    for (int j = 0; j < 4; ++j) acc[i][j] = (f32x4){0.f, 0.f, 0.f, 0.f};

  int a_chunk0 = wave * 2;
  int a_r = lane >> 2;        // row within 16-row chunk
  int a_c = (lane & 3) * 8;   // col element (8 bf16 = 16B)

  for (int kk = 0; kk < D_; kk += 2 * BK) {
    __syncthreads();
    #pragma unroll
    for (int sl = 0; sl < 2; ++sl) {
      #pragma unroll
      for (int j = 0; j < 2; ++j) {
        int chunk = a_chunk0 + j;
        const unsigned short* srcA =
            Abase + (size_t)(chunk * 16 + a_r) * D_ + kk + sl * BK + a_c;
        async_load16(srcA, &Alds[sl][chunk * 512]);
        const unsigned short* srcB =
            Bbase + (size_t)(chunk * 16 + a_r) * D_ + kk + sl * BK + a_c;
        async_load16(srcB, &Blds[sl][chunk * 512]);
      }
    }
    __syncthreads();   // vmcnt(0) drain -> all 16 chunks landed

    int koff = (lane >> 4) * 8;
    int r16  = lane & 15;
    #pragma unroll
    for (int sl = 0; sl < 2; ++sl) {
      bf16x8 af[4], bfr[4];
      #pragma unroll
      for (int mi = 0; mi < 4; ++mi)
        af[mi] = *(const bf16x8*)(&Alds[sl][(wm * 64 + mi * 16 + r16) * BK + koff]);
      #pragma unroll
      for (int ni = 0; ni < 4; ++ni)
        bfr[ni] = *(const bf16x8*)(&Blds[sl][(wn * 64 + ni * 16 + r16) * BK + koff]);
      #pragma unroll
      for (int mi = 0; mi < 4; ++mi)
        #pragma unroll
        for (int ni = 0; ni < 4; ++ni)
          acc[mi][ni] = __builtin_amdgcn_mfma_f32_16x16x32_bf16(
              af[mi], bfr[ni], acc[mi][ni], 0, 0, 0);
    }
  }

  // --- epilogue: y = acc + g0*bias[e0] + g1*bias[e1] ---
  int   e0 = eidx[b], e1 = eidx[B_ + b];
  float g0 = gval[b], g1 = gval[B_ + b];
  float* Y = y + ((size_t)(b * S_ + s0)) * O_ + o0;
  int col   = lane & 15;
  int rquad = (lane >> 4) * 4;
  #pragma unroll
  for (int ni = 0; ni < 4; ++ni) {
    int n = wn * 64 + ni * 16 + col;
    float cbv = g0 * bias[e0 * O_ + o0 + n] + g1 * bias[e1 * O_ + o0 + n];
    #pragma unroll
    for (int mi = 0; mi < 4; ++mi) {
      #pragma unroll
      for (int r = 0; r < 4; ++r) {
        int m = wm * 64 + mi * 16 + rquad + r;
        Y[(size_t)m * O_ + n] = acc[mi][ni][r] + cbv;
      }
    }
  }
}

// ---------------- launcher ----------------
// ws layout (bytes):
//   [0,        1572864)  psum   float[16*32*768]
//   [1572864,  1573888)  gates  float[32*8]
//   [1573888,  1574144)  eidx   int[64]
//   [1574144,  1574400)  gval   float[64]
//   [2097152, 27262976)  x_bf16 ushort[32*512*768]   (25.2 MB)
//   [27262976,65011712)  wc     ushort[32*768*768]   (37.7 MB)
extern "C" void kernel_launch(void* const* d_in, const int* in_sizes, int n_in,
                              void* d_out, int out_size, void* d_ws, size_t ws_size,
                              hipStream_t stream) {
  const float* x      = (const float*)d_in[0];
  const float* w_gate = (const float*)d_in[1];
  const float* weight = (const float*)d_in[2];
  const float* bias   = (const float*)d_in[3];
  float* y = (float*)d_out;

  float* psum  = (float*)d_ws;
  float* gates = (float*)((char*)d_ws + 1572864);
  int*   eidx  = (int*)((char*)d_ws + 1573888);
  float* gval  = (float*)((char*)d_ws + 1574144);
  unsigned short* xb = (unsigned short*)((char*)d_ws + 2097152);
  unsigned short* wc = (unsigned short*)((char*)d_ws + 27262976);

  k_pool_convert<<<dim3(32, 16), 192, 0, stream>>>(x, xb, psum);
  k_logits<<<32, 256, 0, stream>>>(psum, w_gate, gates, eidx, gval);
  k_combine<<<dim3(288, 4), 256, 0, stream>>>(weight, gates, wc, y + YSIZE);
  k_moe_gemm<<<768, 256, 0, stream>>>(xb, wc, eidx, gval, bias, y);
}

// Round 6
// 160.960 us; speedup vs baseline: 1.8686x; 1.0055x over previous
//
#include <hip/hip_runtime.h>
#include <hip/hip_bf16.h>
#include <stdint.h>

#define B_ 32
#define S_ 512
#define D_ 768
#define O_ 768
#define E_ 8
#define YSIZE (B_ * S_ * O_)   // 12582912
#define BK 32
#define WSLICE (O_ * D_)       // 589824 elements per expert / per-b combined slice

typedef __attribute__((ext_vector_type(8))) short bf16x8;
typedef __attribute__((ext_vector_type(4))) float f32x4;

static __device__ __forceinline__ unsigned short f2bf(float f) {
  union { float f; uint32_t u; } v; v.f = f;
  uint32_t u = v.u;
  uint32_t r = u + 0x7fff + ((u >> 16) & 1);   // RNE
  return (unsigned short)(r >> 16);
}

static __device__ __forceinline__ void async_load16(const void* g, void* l) {
  __builtin_amdgcn_global_load_lds(
      (const __attribute__((address_space(1))) void*)g,
      (__attribute__((address_space(3))) void*)l, 16, 0, 0);
}

// ---------------- Kernel 1: pool partial sums + x -> bf16 ----------------
// grid (32, 16), block 192 (3 waves): thread t owns d = 4t..4t+3 (float4).
// psum layout: [b][chunk][d] so k_logits reads contiguous.
__global__ __launch_bounds__(192) void k_pool_convert(
    const float* __restrict__ x, unsigned short* __restrict__ xb,
    float* __restrict__ psum) {
  int t  = threadIdx.x;          // 0..191
  int b  = blockIdx.x;
  int sc = blockIdx.y;           // 0..15, 32 s-rows each
  size_t rowbase = (size_t)(b * S_ + sc * 32) * D_;
  const float* xp = x + rowbase + 4 * t;
  unsigned short* op = xb + rowbase + 4 * t;
  float4 sum = {0.f, 0.f, 0.f, 0.f};
  #pragma unroll 8
  for (int s = 0; s < 32; ++s) {
    float4 v = *(const float4*)(xp + (size_t)s * D_);
    sum.x += v.x; sum.y += v.y; sum.z += v.z; sum.w += v.w;
    ushort4 o;
    o.x = f2bf(v.x); o.y = f2bf(v.y); o.z = f2bf(v.z); o.w = f2bf(v.w);
    *(ushort4*)(op + (size_t)s * D_) = o;
  }
  *(float4*)(psum + (size_t)(b * 16 + sc) * D_ + 4 * t) = sum;
}

// ---------------- Kernel 2a: logits + top-2 + softmax (one block per b) ----
__global__ __launch_bounds__(256) void k_logits(
    const float* __restrict__ psum, const float* __restrict__ w_gate,
    float* __restrict__ gates, int* __restrict__ eidx,
    float* __restrict__ gval) {
  int b = blockIdx.x;
  int tid = threadIdx.x;
  float acc[E_];
  #pragma unroll
  for (int e = 0; e < E_; ++e) acc[e] = 0.f;

  for (int d = tid; d < D_; d += 256) {
    float p = 0.f;
    #pragma unroll
    for (int c = 0; c < 16; ++c) p += psum[(size_t)(b * 16 + c) * D_ + d];
    p *= (1.0f / (float)S_);
    const float* wg = w_gate + d * E_;
    #pragma unroll
    for (int e = 0; e < E_; ++e) acc[e] += p * wg[e];
  }
  #pragma unroll
  for (int off = 32; off > 0; off >>= 1) {
    #pragma unroll
    for (int e = 0; e < E_; ++e) acc[e] += __shfl_down(acc[e], off, 64);
  }
  __shared__ float part[4][E_];
  if ((tid & 63) == 0) {
    #pragma unroll
    for (int e = 0; e < E_; ++e) part[tid >> 6][e] = acc[e];
  }
  __syncthreads();
  if (tid == 0) {
    float lg[E_];
    #pragma unroll
    for (int e = 0; e < E_; ++e)
      lg[e] = part[0][e] + part[1][e] + part[2][e] + part[3][e];
    int i0 = 0; float v0 = lg[0];
    #pragma unroll
    for (int e = 1; e < E_; ++e) { if (lg[e] > v0) { v0 = lg[e]; i0 = e; } }
    int i1 = -1; float v1 = -1e30f;
    #pragma unroll
    for (int e = 0; e < E_; ++e) {
      if (e == i0) continue;
      if (lg[e] > v1) { v1 = lg[e]; i1 = e; }
    }
    float m  = fmaxf(v0, v1);
    float x0 = expf(v0 - m), x1 = expf(v1 - m);
    float s  = x0 + x1;
    float g0 = x0 / s, g1 = x1 / s;
    #pragma unroll
    for (int e = 0; e < E_; ++e)
      gates[b * E_ + e] = (e == i0) ? g0 : ((e == i1) ? g1 : 0.f);
    eidx[b] = i0; eidx[B_ + b] = i1;
    gval[b] = g0; gval[B_ + b] = g1;
  }
}

// ---------------- Kernel 2c: combined weights + fused aux loss ------------
// grid (288, 4), block 256. Unchanged from R4/R5.
__global__ __launch_bounds__(256) void k_combine(
    const float* __restrict__ weight, const float* __restrict__ gates,
    unsigned short* __restrict__ wc, float* __restrict__ loss_out) {
  __shared__ float gsh[B_][E_];
  int tid = threadIdx.x;
  if (tid < B_ * E_) ((float*)gsh)[tid] = gates[tid];
  __syncthreads();

  if (blockIdx.x == 0 && blockIdx.y == 0 && tid == 0) {
    double mi = 0, ml = 0;
    float imp[E_], ldv[E_];
    #pragma unroll
    for (int e = 0; e < E_; ++e) {
      float s = 0.f, c = 0.f;
      for (int b = 0; b < B_; ++b) {
        float g = gsh[b][e];
        s += g; c += (g > 0.f) ? 1.f : 0.f;
      }
      imp[e] = s; ldv[e] = c;
      mi += s; ml += c;
    }
    mi /= E_; ml /= E_;
    double vi = 0, vl = 0;
    #pragma unroll
    for (int e = 0; e < E_; ++e) {
      double di = imp[e] - mi, dl = ldv[e] - ml;
      vi += di * di; vl += dl * dl;
    }
    vi /= (E_ - 1); vl /= (E_ - 1);
    loss_out[0] = (float)((vi / (mi * mi + 1e-10) + vl / (ml * ml + 1e-10)) * 0.01);
  }

  size_t i = (size_t)blockIdx.x * 2048 + tid * 8;
  int b0 = blockIdx.y * 8;
  float v[E_][8];
  #pragma unroll
  for (int e = 0; e < E_; ++e) {
    float4 u0 = *(const float4*)(weight + (size_t)e * WSLICE + i);
    float4 u1 = *(const float4*)(weight + (size_t)e * WSLICE + i + 4);
    v[e][0] = u0.x; v[e][1] = u0.y; v[e][2] = u0.z; v[e][3] = u0.w;
    v[e][4] = u1.x; v[e][5] = u1.y; v[e][6] = u1.z; v[e][7] = u1.w;
  }
  #pragma unroll
  for (int bb = 0; bb < 8; ++bb) {
    int b = b0 + bb;
    float c[8];
    #pragma unroll
    for (int j = 0; j < 8; ++j) c[j] = 0.f;
    #pragma unroll
    for (int e = 0; e < E_; ++e) {
      float g = gsh[b][e];
      #pragma unroll
      for (int j = 0; j < 8; ++j) c[j] += g * v[e][j];
    }
    uint32_t pk[4];
    #pragma unroll
    for (int j = 0; j < 4; ++j)
      pk[j] = (uint32_t)f2bf(c[2 * j]) | ((uint32_t)f2bf(c[2 * j + 1]) << 16);
    *(uint4*)(wc + (size_t)b * WSLICE + i) = make_uint4(pk[0], pk[1], pk[2], pk[3]);
  }
}

// ---------------- Kernel 3: batched GEMM y[b] = x[b] @ Wc[b]^T + bias ------
// 128x128 tile, K-step 64 (two BK=32 slabs per barrier pair), XCD-affine
// grid. LDS 16B-segment XOR swizzle: physical seg p holds logical seg
// p ^ ((row>>1)&3), making fragment ds_read_b128 2-way (free) instead of
// 8-way bank-aliased. DMA dst stays lane-linear (required); the swizzle is
// applied to the *global source column* at staging time.
__global__ __launch_bounds__(256, 3) void k_moe_gemm(
    const unsigned short* __restrict__ xb, const unsigned short* __restrict__ wc,
    const int* __restrict__ eidx, const float* __restrict__ gval,
    const float* __restrict__ bias, float* __restrict__ y) {
  __shared__ unsigned short Alds[2][128 * BK];  // 2 x 8 KB
  __shared__ unsigned short Blds[2][128 * BK];  // 2 x 8 KB

  int flat = blockIdx.x;          // 0..767
  int xcd  = flat & 7;
  int slot = flat >> 3;           // 0..95
  int b    = xcd + 8 * (slot / 24);
  int tile = slot % 24;
  int st = tile & 3;              // S tile 0..3
  int ot = tile >> 2;             // O tile 0..5
  int s0 = st * 128, o0 = ot * 128;

  int tid  = threadIdx.x;
  int wave = tid >> 6, lane = tid & 63;
  int wm = wave & 1, wn = wave >> 1;

  const unsigned short* Abase = xb + ((size_t)(b * S_ + s0)) * D_;
  const unsigned short* Bbase = wc + (size_t)b * WSLICE + (size_t)o0 * D_;

  f32x4 acc[4][4];
  #pragma unroll
  for (int i = 0; i < 4; ++i)
    #pragma unroll
    for (int j = 0; j < 4; ++j) acc[i][j] = (f32x4){0.f, 0.f, 0.f, 0.f};

  int a_chunk0 = wave * 2;
  int a_r = lane >> 2;                              // row within 16-row chunk
  int a_c = (((lane & 3) ^ ((a_r >> 1) & 3))) * 8;  // swizzled source column

  for (int kk = 0; kk < D_; kk += 2 * BK) {
    __syncthreads();
    #pragma unroll
    for (int sl = 0; sl < 2; ++sl) {
      #pragma unroll
      for (int j = 0; j < 2; ++j) {
        int chunk = a_chunk0 + j;
        const unsigned short* srcA =
            Abase + (size_t)(chunk * 16 + a_r) * D_ + kk + sl * BK + a_c;
        async_load16(srcA, &Alds[sl][chunk * 512]);
        const unsigned short* srcB =
            Bbase + (size_t)(chunk * 16 + a_r) * D_ + kk + sl * BK + a_c;
        async_load16(srcB, &Blds[sl][chunk * 512]);
      }
    }
    __syncthreads();   // vmcnt(0) drain -> all 16 chunks landed

    int s   = lane >> 4;                   // logical 16B segment (k/8)
    int r16 = lane & 15;
    int kphys = (s ^ ((r16 >> 1) & 3)) * 8;  // swizzled physical segment
    #pragma unroll
    for (int sl = 0; sl < 2; ++sl) {
      bf16x8 af[4], bfr[4];
      #pragma unroll
      for (int mi = 0; mi < 4; ++mi)
        af[mi] = *(const bf16x8*)(&Alds[sl][(wm * 64 + mi * 16 + r16) * BK + kphys]);
      #pragma unroll
      for (int ni = 0; ni < 4; ++ni)
        bfr[ni] = *(const bf16x8*)(&Blds[sl][(wn * 64 + ni * 16 + r16) * BK + kphys]);
      #pragma unroll
      for (int mi = 0; mi < 4; ++mi)
        #pragma unroll
        for (int ni = 0; ni < 4; ++ni)
          acc[mi][ni] = __builtin_amdgcn_mfma_f32_16x16x32_bf16(
              af[mi], bfr[ni], acc[mi][ni], 0, 0, 0);
    }
  }

  // --- epilogue: y = acc + g0*bias[e0] + g1*bias[e1] ---
  int   e0 = eidx[b], e1 = eidx[B_ + b];
  float g0 = gval[b], g1 = gval[B_ + b];
  float* Y = y + ((size_t)(b * S_ + s0)) * O_ + o0;
  int col   = lane & 15;
  int rquad = (lane >> 4) * 4;
  #pragma unroll
  for (int ni = 0; ni < 4; ++ni) {
    int n = wn * 64 + ni * 16 + col;
    float cbv = g0 * bias[e0 * O_ + o0 + n] + g1 * bias[e1 * O_ + o0 + n];
    #pragma unroll
    for (int mi = 0; mi < 4; ++mi) {
      #pragma unroll
      for (int r = 0; r < 4; ++r) {
        int m = wm * 64 + mi * 16 + rquad + r;
        Y[(size_t)m * O_ + n] = acc[mi][ni][r] + cbv;
      }
    }
  }
}

// ---------------- launcher ----------------
// ws layout (bytes):
//   [0,        1572864)  psum   float[32*16*768]
//   [1572864,  1573888)  gates  float[32*8]
//   [1573888,  1574144)  eidx   int[64]
//   [1574144,  1574400)  gval   float[64]
//   [2097152, 27262976)  x_bf16 ushort[32*512*768]   (25.2 MB)
//   [27262976,65011712)  wc     ushort[32*768*768]   (37.7 MB)
extern "C" void kernel_launch(void* const* d_in, const int* in_sizes, int n_in,
                              void* d_out, int out_size, void* d_ws, size_t ws_size,
                              hipStream_t stream) {
  const float* x      = (const float*)d_in[0];
  const float* w_gate = (const float*)d_in[1];
  const float* weight = (const float*)d_in[2];
  const float* bias   = (const float*)d_in[3];
  float* y = (float*)d_out;

  float* psum  = (float*)d_ws;
  float* gates = (float*)((char*)d_ws + 1572864);
  int*   eidx  = (int*)((char*)d_ws + 1573888);
  float* gval  = (float*)((char*)d_ws + 1574144);
  unsigned short* xb = (unsigned short*)((char*)d_ws + 2097152);
  unsigned short* wc = (unsigned short*)((char*)d_ws + 27262976);

  k_pool_convert<<<dim3(32, 16), 192, 0, stream>>>(x, xb, psum);
  k_logits<<<32, 256, 0, stream>>>(psum, w_gate, gates, eidx, gval);
  k_combine<<<dim3(288, 4), 256, 0, stream>>>(weight, gates, wc, y + YSIZE);
  k_moe_gemm<<<768, 256, 0, stream>>>(xb, wc, eidx, gval, bias, y);
}